// Round 14
// baseline (5564.901 us; speedup 1.0000x reference)
//
#include <hip/hip_runtime.h>
#include <hip/hip_bf16.h>

typedef short s8v __attribute__((ext_vector_type(8)));
typedef float f4v __attribute__((ext_vector_type(4)));
typedef unsigned int u4v __attribute__((ext_vector_type(4)));
typedef unsigned int u2v __attribute__((ext_vector_type(2)));

#define NBLK 64
#define TPB 512

constexpr int BB = 32, TT = 512, DD = 512, HH = 1024;
constexpr int KK = DD + HH;          // 1536
constexpr int PK = KK + 8;           // padded LDS K-stride
constexpr int PK8 = PK / 8;
constexpr int K8 = KK / 8;
constexpr size_t BBHH = (size_t)BB * HH;

// ---- workspace layout (bytes) ----
constexpr size_t OFF_WGT = 0;
constexpr size_t SZ_WGT  = (size_t)2 * HH * KK * 2;
constexpr size_t OFF_WCT = OFF_WGT + SZ_WGT;
constexpr size_t SZ_WCT  = (size_t)HH * KK * 2;
constexpr size_t OFF_XBF = OFF_WCT + SZ_WCT;
constexpr size_t SZ_XBF  = (size_t)BB * TT * DD * 2;
constexpr size_t OFF_HPB = OFF_XBF + SZ_XBF;                    // h publish (depth-1)
constexpr size_t SZ_PUB  = BBHH * 2;                            // 65,536
constexpr size_t OFF_RPB = OFF_HPB + SZ_PUB;                    // rh publish (depth-2)
constexpr size_t OFF_FLG = OFF_RPB + 2 * SZ_PUB;                // r7 flag layout
constexpr size_t SZ_FLG  = (size_t)2 * NBLK * 2 * 16 * 4;       // 16,384

// ---------------------------------------------------------------------------
__global__ void wtr_kernel(const float* __restrict__ in, unsigned short* __restrict__ out, int N) {
    __shared__ float tl[32][33];
    int tx = threadIdx.x & 31, ty = threadIdx.x >> 5;
    int n0 = blockIdx.x * 32, k0 = blockIdx.y * 32;
#pragma unroll
    for (int r = ty; r < 32; r += 8) tl[r][tx] = in[(size_t)(k0 + r) * N + n0 + tx];
    __syncthreads();
#pragma unroll
    for (int r = ty; r < 32; r += 8) {
        __hip_bfloat16 h = __float2bfloat16(tl[tx][r]);
        out[(size_t)(n0 + r) * KK + k0 + tx] = *reinterpret_cast<unsigned short*>(&h);
    }
}

__global__ void xconv_kernel(const float* __restrict__ X, unsigned short* __restrict__ Xbf) {
    size_t i = ((size_t)blockIdx.x * 256 + threadIdx.x) * 4;
    float4 v = *reinterpret_cast<const float4*>(X + i);
    __hip_bfloat16 h0 = __float2bfloat16(v.x), h1 = __float2bfloat16(v.y);
    __hip_bfloat16 h2 = __float2bfloat16(v.z), h3 = __float2bfloat16(v.w);
    ushort4 o;
    o.x = *(unsigned short*)&h0; o.y = *(unsigned short*)&h1;
    o.z = *(unsigned short*)&h2; o.w = *(unsigned short*)&h3;
    *reinterpret_cast<ushort4*>(Xbf + i) = o;
}

// ---------------------------------------------------------------------------
// Coherent primitives (sc0 sc1 = system scope; proven r2-r13).
// Generation-in-exponent protocol: value published at step t is h*2^(32*(t&3))
// (|h| clamped to >=2^-30, so bf16 exponent lies in a disjoint 32-wide window
// per class). Consumers validate each dword's exp[7:5] against the expected
// class; stale data (t-1 in hpub, t-2 in rpub-slot) is a different class mod 4
// and is rejected; decode = one exact power-of-2 multiply of the separated
// h-accumulator. Flags exist only as a slow-path wait hint (no producer drain).
__device__ __forceinline__ u4v cload16(const void* p) {
    u4v r; asm volatile("global_load_dwordx4 %0, %1, off sc0 sc1" : "=v"(r) : "v"(p) : "memory"); return r;
}
__device__ __forceinline__ void cstore8(void* p, u2v v) {
    asm volatile("global_store_dwordx2 %0, %1, off sc0 sc1" :: "v"(p), "v"(v) : "memory");
}
__device__ __forceinline__ void cstore4(void* p, int v) {
    asm volatile("global_store_dword %0, %1, off sc0 sc1" :: "v"(p), "v"(v) : "memory");
}
#define B16(x) __builtin_bit_cast(s8v, (x))
#define WAIT_VM(n) do { asm volatile("s_waitcnt vmcnt(" #n ")" ::: "memory"); \
                        __builtin_amdgcn_sched_barrier(0); } while (0)

__device__ __forceinline__ void poll16(const int* f, int blk0, int rtw, int gen, int lane) {
    if (lane < 16) {
        const int* fp = f + ((size_t)(blk0 + lane) * 2 + rtw) * 16;
        while (__hip_atomic_load(fp, __ATOMIC_RELAXED, __HIP_MEMORY_SCOPE_AGENT) < gen)
            __builtin_amdgcn_s_sleep(1);
    }
    asm volatile("" ::: "memory");
}

#define MFMA(A, B, C) __builtin_amdgcn_mfma_f32_16x16x32_bf16((A), (B), (C), 0, 0, 0)

// encode: clamp |h|>=2^-30 (err ~1e-9), scale by class factor (exact)
__device__ __forceinline__ float enc(float h, float s) {
    float a = __builtin_fmaxf(__builtin_fabsf(h), 9.313225746154785e-10f);
    return __builtin_copysignf(a, h) * s;
}
// class helpers: scale 2^(32c), inverse 2^(-32c), expected exp[7:5] pattern
__device__ __forceinline__ float cls_scale(int c) {
    return __builtin_bit_cast(float, (unsigned)(127 + 32 * c) << 23);
}
__device__ __forceinline__ float cls_inv(int c) {
    return __builtin_bit_cast(float, (unsigned)(127 - 32 * c) << 23);
}
__device__ __forceinline__ unsigned cls_pat(int c) {
    return 0x30003000u + (unsigned)c * 0x10001000u;
}
#define VALID8(arr, e, bad) do { bad = 0u; \
    _Pragma("unroll") for (int j_ = 0; j_ < 8; ++j_) { \
        bad |= ((arr)[j_][0] & 0x70007000u) ^ (e); \
        bad |= ((arr)[j_][1] & 0x70007000u) ^ (e); \
        bad |= ((arr)[j_][2] & 0x70007000u) ^ (e); \
        bad |= ((arr)[j_][3] & 0x70007000u) ^ (e); } } while (0)

// ---------------------------------------------------------------------------
// Persistent kernel, 64 blocks x 512 threads (8 waves), 1 block/CU.
// Block b owns r/u/cand columns [b*16, b*16+16).
// Waves: ks = wid>>1 (4-way K-split), rt = wid&1 (16-row batch tile).
__global__ __launch_bounds__(TPB, 1) void gru_kernel(
    const unsigned short* __restrict__ Xbf,
    const unsigned short* __restrict__ WgT,
    const unsigned short* __restrict__ WcT,
    const float* __restrict__ bg,
    const float* __restrict__ bc,
    float* __restrict__ out,
    unsigned short* __restrict__ hpub,
    unsigned short* __restrict__ rpub,
    int* __restrict__ gflagA,
    int* __restrict__ gflagB)
{
    __shared__ unsigned short sWg[32 * PK];        // 98,816 B
    __shared__ unsigned short sWc[16 * PK];        // 49,408 B
    __shared__ float sP[3][2][2][16][16];          // 12,288 B
    __shared__ unsigned short sStage[2][16][16];   //  1,024 B

    const int b    = blockIdx.x;
    const int tid  = threadIdx.x;
    const int wid  = tid >> 6;
    const int lane = tid & 63;
    const int l15  = lane & 15;
    const int lq   = lane >> 4;
    const int ks   = wid >> 1;
    const int rt   = wid & 1;
    const int roff = rt * 16;
    const int arow = roff + l15;
    const int bcol0= b * 16;

    // ---- stage weight slices into LDS (once) ----
    {
        s8v* dst = (s8v*)sWg;
        for (int idx = tid; idx < 32 * K8; idx += TPB) {
            int c = idx / K8, k8 = idx % K8;
            int gc = (c < 16) ? (bcol0 + c) : (HH + bcol0 + (c - 16));
            dst[c * PK8 + k8] = ((const s8v*)(WgT + (size_t)gc * KK))[k8];
        }
        s8v* dst2 = (s8v*)sWc;
        for (int idx = tid; idx < 16 * K8; idx += TPB) {
            int c = idx / K8, k8 = idx % K8;
            dst2[c * PK8 + k8] = ((const s8v*)(WcT + (size_t)(bcol0 + c) * KK))[k8];
        }
    }

    const float bgr  = bg[bcol0 + l15];
    const float bgu  = bg[HH + bcol0 + l15];
    const float bcv  = bc[bcol0 + l15];
    const int   ccol = bcol0 + l15;

    const s8v* sWg8 = (const s8v*)sWg;
    const s8v* sWc8 = (const s8v*)sWc;
    const s8v* bwr = sWg8 + l15 * PK8 + lq;          // r-col weights
    const s8v* bwu = sWg8 + (16 + l15) * PK8 + lq;   // u-col weights
    const s8v* bwc = sWc8 + l15 * PK8 + lq;          // cand weights
    const s8v* bwrx = bwr + 16 * ks;                 // x chunks [4ks..4ks+4)
    const s8v* bwux = bwu + 16 * ks;
    const s8v* bwrh = bwr + 64 + 32 * ks;            // h chunks [8ks..8ks+8)
    const s8v* bwuh = bwu + 64 + 32 * ks;
    const s8v* bwcx = bwc + 16 * ks;
    const s8v* bwch = bwc + 64 + 32 * ks;

    float hprev[4] = {0.f, 0.f, 0.f, 0.f};   // valid in ks==0 waves
    float ureg[4]  = {0.f, 0.f, 0.f, 0.f};

    __syncthreads();

#pragma unroll 1
    for (int t = 0; t < TT; ++t) {
        const s8v* xk = (const s8v*)(Xbf + (size_t)arow * (TT * DD) + (size_t)t * DD) + lq + 16 * ks;
        s8v x0 = xk[0], x1 = xk[4], x2 = xk[8], x3 = xk[12];   // shared by A & B

        // ========== Phase A: speculative h loads -> x-MFMAs -> validate ==========
        u4v hb[8];
        const unsigned short* hp = hpub + (size_t)arow * HH + ks * 256 + lq * 8;
        if (t > 0) {
#pragma unroll
            for (int j = 0; j < 8; ++j) hb[j] = cload16(hp + (size_t)j * 32);
        }
        f4v axr = {0,0,0,0}, axu = {0,0,0,0};
        axr = MFMA(x0, bwrx[0],  axr); axu = MFMA(x0, bwux[0],  axu);
        axr = MFMA(x1, bwrx[4],  axr); axu = MFMA(x1, bwux[4],  axu);
        axr = MFMA(x2, bwrx[8],  axr); axu = MFMA(x2, bwux[8],  axu);
        axr = MFMA(x3, bwrx[12], axr); axu = MFMA(x3, bwux[12], axu);

        f4v ahr0 = {0,0,0,0}, ahr1 = {0,0,0,0}, ahu0 = {0,0,0,0}, ahu1 = {0,0,0,0};
        if (t > 0) {
            WAIT_VM(0);
            const unsigned eA = cls_pat((t - 1) & 3);
            unsigned bad; VALID8(hb, eA, bad);
            if (__any(bad != 0)) {                    // slow path: flag wait + revalidate
                poll16(gflagB, ks * 16, rt, t, lane);
                do {
#pragma unroll
                    for (int j = 0; j < 8; ++j) hb[j] = cload16(hp + (size_t)j * 32);
                    WAIT_VM(0);
                    VALID8(hb, eA, bad);
                } while (__any(bad != 0));
            }
            ahr0 = MFMA(B16(hb[0]), bwrh[0],  ahr0); ahu0 = MFMA(B16(hb[0]), bwuh[0],  ahu0);
            ahr1 = MFMA(B16(hb[1]), bwrh[4],  ahr1); ahu1 = MFMA(B16(hb[1]), bwuh[4],  ahu1);
            ahr0 = MFMA(B16(hb[2]), bwrh[8],  ahr0); ahu0 = MFMA(B16(hb[2]), bwuh[8],  ahu0);
            ahr1 = MFMA(B16(hb[3]), bwrh[12], ahr1); ahu1 = MFMA(B16(hb[3]), bwuh[12], ahu1);
            ahr0 = MFMA(B16(hb[4]), bwrh[16], ahr0); ahu0 = MFMA(B16(hb[4]), bwuh[16], ahu0);
            ahr1 = MFMA(B16(hb[5]), bwrh[20], ahr1); ahu1 = MFMA(B16(hb[5]), bwuh[20], ahu1);
            ahr0 = MFMA(B16(hb[6]), bwrh[24], ahr0); ahu0 = MFMA(B16(hb[6]), bwuh[24], ahu0);
            ahr1 = MFMA(B16(hb[7]), bwrh[28], ahr1); ahu1 = MFMA(B16(hb[7]), bwuh[28], ahu1);
        }
        const float hinv = cls_inv((t - 1) & 3);      // t==0: ah accs are zero anyway
        f4v pr = axr + (ahr0 + ahr1) * hinv;
        f4v pu = axu + (ahu0 + ahu1) * hinv;

        // ---- cross-wave K-reduction ----
        if (ks > 0) {
#pragma unroll
            for (int i = 0; i < 4; ++i) {
                sP[ks - 1][rt][0][lq * 4 + i][l15] = pr[i];
                sP[ks - 1][rt][1][lq * 4 + i][l15] = pu[i];
            }
        }
        __syncthreads();                             // S1: A partials ready
        float zr[4], zu[4];
        if (ks == 0) {
#pragma unroll
            for (int i = 0; i < 4; ++i) {
                int rr = lq * 4 + i;
                zr[i] = pr[i] + sP[0][rt][0][rr][l15] + sP[1][rt][0][rr][l15]
                              + sP[2][rt][0][rr][l15] + bgr;
                zu[i] = pu[i] + sP[0][rt][1][rr][l15] + sP[1][rt][1][rr][l15]
                              + sP[2][rt][1][rr][l15] + bgu;
            }
        }
        __syncthreads();                             // S2: sP free for phase B
        const float sEnc = cls_scale(t & 3);
        if (ks == 0) {
#pragma unroll
            for (int i = 0; i < 4; ++i) {
                float r = 1.f / (1.f + __expf(-zr[i]));
                ureg[i] = 1.f / (1.f + __expf(-zu[i]));
                __hip_bfloat16 hb16 = __float2bfloat16(enc(r * hprev[i], sEnc));
                sStage[rt][lq * 4 + i][l15] = *(unsigned short*)&hb16;
            }
            if (t > 0) {                             // rh slot never read at t=0
                int prow = lane >> 2, pc4 = (lane & 3) * 4;
                u2v v = *reinterpret_cast<const u2v*>(&sStage[rt][prow][pc4]);  // same-wave LDS
                cstore8(rpub + (size_t)(t & 1) * BBHH + (size_t)(roff + prow) * HH + bcol0 + pc4, v);
                // no drain — flag is a hint; data self-validates
                if (lane == 0) cstore4(gflagA + (b * 2 + rt) * 16, t);
            }
        }

        // ========== Phase B: speculative rh loads -> x-MFMAs -> validate ==========
        u4v rb[8];
        const unsigned short* rp = rpub + (size_t)(t & 1) * BBHH
                                 + (size_t)arow * HH + ks * 256 + lq * 8;
        if (t > 0) {
#pragma unroll
            for (int j = 0; j < 8; ++j) rb[j] = cload16(rp + (size_t)j * 32);
        }
        f4v cx0 = {0,0,0,0}, cx1 = {0,0,0,0};
        cx0 = MFMA(x0, bwcx[0],  cx0); cx1 = MFMA(x1, bwcx[4],  cx1);
        cx0 = MFMA(x2, bwcx[8],  cx0); cx1 = MFMA(x3, bwcx[12], cx1);

        f4v ch0 = {0,0,0,0}, ch1 = {0,0,0,0};
        if (t > 0) {
            WAIT_VM(0);
            const unsigned eB = cls_pat(t & 3);
            unsigned bad; VALID8(rb, eB, bad);
            if (__any(bad != 0)) {
                poll16(gflagA, ks * 16, rt, t, lane);
                do {
#pragma unroll
                    for (int j = 0; j < 8; ++j) rb[j] = cload16(rp + (size_t)j * 32);
                    WAIT_VM(0);
                    VALID8(rb, eB, bad);
                } while (__any(bad != 0));
            }
            ch0 = MFMA(B16(rb[0]), bwch[0],  ch0); ch1 = MFMA(B16(rb[1]), bwch[4],  ch1);
            ch0 = MFMA(B16(rb[2]), bwch[8],  ch0); ch1 = MFMA(B16(rb[3]), bwch[12], ch1);
            ch0 = MFMA(B16(rb[4]), bwch[16], ch0); ch1 = MFMA(B16(rb[5]), bwch[20], ch1);
            ch0 = MFMA(B16(rb[6]), bwch[24], ch0); ch1 = MFMA(B16(rb[7]), bwch[28], ch1);
        }
        const float rinv = cls_inv(t & 3);
        f4v pc = (cx0 + cx1) + (ch0 + ch1) * rinv;

        if (ks > 0) {
#pragma unroll
            for (int i = 0; i < 4; ++i) sP[ks - 1][rt][0][lq * 4 + i][l15] = pc[i];
        }
        __syncthreads();                             // S3: B partials ready
        float zc[4];
        if (ks == 0) {
#pragma unroll
            for (int i = 0; i < 4; ++i) {
                int rr = lq * 4 + i;
                zc[i] = pc[i] + sP[0][rt][0][rr][l15] + sP[1][rt][0][rr][l15]
                              + sP[2][rt][0][rr][l15] + bcv;
            }
        }
        __syncthreads();                             // S4: sP free for next step
        if (ks == 0) {
#pragma unroll
            for (int i = 0; i < 4; ++i) {
                float e = __expf(2.f * zc[i]);
                float cv = 1.f - 2.f / (e + 1.f);
                float hn = ureg[i] * hprev[i] + (1.f - ureg[i]) * cv;
                hprev[i] = hn;
                __hip_bfloat16 hb16 = __float2bfloat16(enc(hn, sEnc));
                sStage[rt][lq * 4 + i][l15] = *(unsigned short*)&hb16;
            }
            int prow = lane >> 2, pc4 = (lane & 3) * 4;
            u2v v = *reinterpret_cast<const u2v*>(&sStage[rt][prow][pc4]);      // same-wave LDS
            cstore8(hpub + (size_t)(roff + prow) * HH + bcol0 + pc4, v);
            // no drain — flag is a hint; data self-validates
            if (lane == 0) cstore4(gflagB + (b * 2 + rt) * 16, t + 1);
            // out stores — off the rendezvous critical path (decoded domain)
#pragma unroll
            for (int i = 0; i < 4; ++i) {
                int row = roff + lq * 4 + i;
                out[(size_t)row * (TT * HH) + (size_t)t * HH + ccol] = hprev[i];
            }
        }
    }
}

// ---------------------------------------------------------------------------
extern "C" void kernel_launch(void* const* d_in, const int* in_sizes, int n_in,
                              void* d_out, int out_size, void* d_ws, size_t ws_size,
                              hipStream_t stream) {
    const float* X  = (const float*)d_in[0];
    const float* gk = (const float*)d_in[1];
    const float* gb = (const float*)d_in[2];
    const float* ck = (const float*)d_in[3];
    const float* cb = (const float*)d_in[4];
    float* out = (float*)d_out;
    char* ws = (char*)d_ws;
    if (ws_size < OFF_FLG + SZ_FLG) return;

    unsigned short* WgT  = (unsigned short*)(ws + OFF_WGT);
    unsigned short* WcT  = (unsigned short*)(ws + OFF_WCT);
    unsigned short* Xbf  = (unsigned short*)(ws + OFF_XBF);
    unsigned short* hpub = (unsigned short*)(ws + OFF_HPB);
    unsigned short* rpub = (unsigned short*)(ws + OFF_RPB);
    int*            gflagA = (int*)(ws + OFF_FLG);
    int*            gflagB = gflagA + NBLK * 2 * 16;

    // 0x7F = exp[7:5] pattern 111 -> fails every class check (cross-launch safe)
    hipMemsetAsync(hpub, 0x7F, 3 * SZ_PUB, stream);
    hipMemsetAsync(gflagA, 0, SZ_FLG, stream);

    dim3 tb(256);
    wtr_kernel<<<dim3(2 * HH / 32, KK / 32), tb, 0, stream>>>(gk, WgT, 2 * HH);
    wtr_kernel<<<dim3(HH / 32, KK / 32), tb, 0, stream>>>(ck, WcT, HH);
    xconv_kernel<<<(BB * TT * DD) / (256 * 4), tb, 0, stream>>>(X, Xbf);

    gru_kernel<<<NBLK, dim3(TPB), 0, stream>>>(Xbf, WgT, WcT, gb, cb, out,
                                               hpub, rpub, gflagA, gflagB);
}

// Round 15
// 5038.495 us; speedup vs baseline: 1.1045x; 1.1045x over previous
//
#include <hip/hip_runtime.h>
#include <hip/hip_bf16.h>

typedef short s8v __attribute__((ext_vector_type(8)));
typedef float f4v __attribute__((ext_vector_type(4)));
typedef unsigned int u4v __attribute__((ext_vector_type(4)));
typedef unsigned int u2v __attribute__((ext_vector_type(2)));

#define NBLK 64
#define TPB 512

constexpr int BB = 32, TT = 512, DD = 512, HH = 1024;
constexpr int KK = DD + HH;          // 1536
constexpr int PK = KK + 8;           // padded LDS K-stride
constexpr int PK8 = PK / 8;
constexpr int K8 = KK / 8;

// ---- workspace layout (bytes) ----
constexpr size_t OFF_WGT = 0;
constexpr size_t SZ_WGT  = (size_t)2 * HH * KK * 2;
constexpr size_t OFF_WCT = OFF_WGT + SZ_WGT;
constexpr size_t SZ_WCT  = (size_t)HH * KK * 2;
constexpr size_t OFF_XBF = OFF_WCT + SZ_WCT;
constexpr size_t SZ_XBF  = (size_t)BB * TT * DD * 2;
constexpr size_t OFF_HPB = OFF_XBF + SZ_XBF;                    // h publish (depth-1, hot)
constexpr size_t SZ_PUB  = (size_t)BB * HH * 2;                 // 65,536
constexpr size_t OFF_RPB = OFF_HPB + SZ_PUB;                    // rh publish (depth-1, hot)
constexpr size_t NEED    = OFF_RPB + SZ_PUB;

// ---------------------------------------------------------------------------
__global__ void wtr_kernel(const float* __restrict__ in, unsigned short* __restrict__ out, int N) {
    __shared__ float tl[32][33];
    int tx = threadIdx.x & 31, ty = threadIdx.x >> 5;
    int n0 = blockIdx.x * 32, k0 = blockIdx.y * 32;
#pragma unroll
    for (int r = ty; r < 32; r += 8) tl[r][tx] = in[(size_t)(k0 + r) * N + n0 + tx];
    __syncthreads();
#pragma unroll
    for (int r = ty; r < 32; r += 8) {
        __hip_bfloat16 h = __float2bfloat16(tl[tx][r]);
        out[(size_t)(n0 + r) * KK + k0 + tx] = *reinterpret_cast<unsigned short*>(&h);
    }
}

__global__ void xconv_kernel(const float* __restrict__ X, unsigned short* __restrict__ Xbf) {
    size_t i = ((size_t)blockIdx.x * 256 + threadIdx.x) * 4;
    float4 v = *reinterpret_cast<const float4*>(X + i);
    __hip_bfloat16 h0 = __float2bfloat16(v.x), h1 = __float2bfloat16(v.y);
    __hip_bfloat16 h2 = __float2bfloat16(v.z), h3 = __float2bfloat16(v.w);
    ushort4 o;
    o.x = *(unsigned short*)&h0; o.y = *(unsigned short*)&h1;
    o.z = *(unsigned short*)&h2; o.w = *(unsigned short*)&h3;
    *reinterpret_cast<ushort4*>(Xbf + i) = o;
}

// ---------------------------------------------------------------------------
// FLAGLESS generation-in-exponent rendezvous (sc0 sc1 = system scope, proven
// r2-r14). Published value at step t is v*2^(32*(t&3)), |v| clamped >= 2^-30,
// so the bf16 exponent's top-3 bits identify the generation class mod 4.
// Stale slot content is always a different class -> each dword self-validates.
// Producers just store (no drain, no flag). Consumers retry-load only stale
// lines; the vmcnt wait paces the spin at one IF round-trip per iteration.
// Decode = one exact power-of-2 multiply on the separated h-accumulator.
__device__ __forceinline__ u4v cload16(const void* p) {
    u4v r; asm volatile("global_load_dwordx4 %0, %1, off sc0 sc1" : "=v"(r) : "v"(p) : "memory"); return r;
}
__device__ __forceinline__ void cstore8(void* p, u2v v) {
    asm volatile("global_store_dwordx2 %0, %1, off sc0 sc1" :: "v"(p), "v"(v) : "memory");
}
#define B16(x) __builtin_bit_cast(s8v, (x))
#define WAIT_VM(n) do { asm volatile("s_waitcnt vmcnt(" #n ")" ::: "memory"); \
                        __builtin_amdgcn_sched_barrier(0); } while (0)

#define MFMA(A, B, C) __builtin_amdgcn_mfma_f32_16x16x32_bf16((A), (B), (C), 0, 0, 0)

// encode: clamp |v|>=2^-30 (abs err <=1e-9), scale by exact power of 2
__device__ __forceinline__ float enc(float v, float s) {
    float a = __builtin_fmaxf(__builtin_fabsf(v), 9.313225746154785e-10f);
    return __builtin_copysignf(a, v) * s;
}
__device__ __forceinline__ float cls_scale(int c) {
    return __builtin_bit_cast(float, (unsigned)(127 + 32 * c) << 23);
}
__device__ __forceinline__ float cls_inv(int c) {
    return __builtin_bit_cast(float, (unsigned)(127 - 32 * c) << 23);
}
__device__ __forceinline__ unsigned cls_pat(int c) {   // expected exp[7:5] bits per half
    return 0x30003000u + (unsigned)c * 0x10001000u;
}
// per-line staleness mask over 8 x 16B lines
__device__ __forceinline__ unsigned check8(const u4v* a, unsigned e) {
    unsigned m = 0;
#pragma unroll
    for (int j = 0; j < 8; ++j) {
        unsigned bj = ((a[j][0] & 0x70007000u) ^ e) | ((a[j][1] & 0x70007000u) ^ e)
                    | ((a[j][2] & 0x70007000u) ^ e) | ((a[j][3] & 0x70007000u) ^ e);
        m |= (bj ? 1u : 0u) << j;
    }
    return m;
}

// ---------------------------------------------------------------------------
// Persistent kernel, 64 blocks x 512 threads (8 waves), 1 block/CU.
// Structure byte-identical to r7 (champion) except the rendezvous protocol.
// Block b owns r/u/cand columns [b*16, b*16+16).
// Waves: ks = wid>>1 (4-way K-split), rt = wid&1 (16-row batch tile).
__global__ __launch_bounds__(TPB, 1) void gru_kernel(
    const unsigned short* __restrict__ Xbf,
    const unsigned short* __restrict__ WgT,
    const unsigned short* __restrict__ WcT,
    const float* __restrict__ bg,
    const float* __restrict__ bc,
    float* __restrict__ out,
    unsigned short* __restrict__ hpub,
    unsigned short* __restrict__ rpub)
{
    __shared__ unsigned short sWg[32 * PK];        // 98,816 B
    __shared__ unsigned short sWc[16 * PK];        // 49,408 B
    __shared__ float sP[3][2][2][16][16];          // 12,288 B
    __shared__ unsigned short sStage[2][16][16];   //  1,024 B

    const int b    = blockIdx.x;
    const int tid  = threadIdx.x;
    const int wid  = tid >> 6;
    const int lane = tid & 63;
    const int l15  = lane & 15;
    const int lq   = lane >> 4;
    const int ks   = wid >> 1;
    const int rt   = wid & 1;
    const int roff = rt * 16;
    const int arow = roff + l15;
    const int bcol0= b * 16;

    // ---- stage weight slices into LDS (once) ----
    {
        s8v* dst = (s8v*)sWg;
        for (int idx = tid; idx < 32 * K8; idx += TPB) {
            int c = idx / K8, k8 = idx % K8;
            int gc = (c < 16) ? (bcol0 + c) : (HH + bcol0 + (c - 16));
            dst[c * PK8 + k8] = ((const s8v*)(WgT + (size_t)gc * KK))[k8];
        }
        s8v* dst2 = (s8v*)sWc;
        for (int idx = tid; idx < 16 * K8; idx += TPB) {
            int c = idx / K8, k8 = idx % K8;
            dst2[c * PK8 + k8] = ((const s8v*)(WcT + (size_t)(bcol0 + c) * KK))[k8];
        }
    }

    const float bgr  = bg[bcol0 + l15];
    const float bgu  = bg[HH + bcol0 + l15];
    const float bcv  = bc[bcol0 + l15];
    const int   ccol = bcol0 + l15;

    const s8v* sWg8 = (const s8v*)sWg;
    const s8v* sWc8 = (const s8v*)sWc;
    const s8v* bwr = sWg8 + l15 * PK8 + lq;          // r-col weights
    const s8v* bwu = sWg8 + (16 + l15) * PK8 + lq;   // u-col weights
    const s8v* bwc = sWc8 + l15 * PK8 + lq;          // cand weights
    const s8v* bwrx = bwr + 16 * ks;                 // x chunks [4ks..4ks+4)
    const s8v* bwux = bwu + 16 * ks;
    const s8v* bwrh = bwr + 64 + 32 * ks;            // h chunks [8ks..8ks+8)
    const s8v* bwuh = bwu + 64 + 32 * ks;
    const s8v* bwcx = bwc + 16 * ks;
    const s8v* bwch = bwc + 64 + 32 * ks;

    float hprev[4] = {0.f, 0.f, 0.f, 0.f};   // valid in ks==0 waves
    float ureg[4]  = {0.f, 0.f, 0.f, 0.f};

    __syncthreads();

#pragma unroll 1
    for (int t = 0; t < TT; ++t) {
        const s8v* xk = (const s8v*)(Xbf + (size_t)arow * (TT * DD) + (size_t)t * DD) + lq + 16 * ks;
        s8v x0 = xk[0], x1 = xk[4], x2 = xk[8], x3 = xk[12];   // shared by A & B

        // ========== Phase A: issue h loads -> x-MFMAs in shadow -> validate-spin ==========
        u4v hb[8];
        const unsigned short* hp = hpub + (size_t)arow * HH + ks * 256 + lq * 8;
        if (t > 0) {
#pragma unroll
            for (int j = 0; j < 8; ++j) hb[j] = cload16(hp + (size_t)j * 32);
        }
        f4v axr = {0,0,0,0}, axu = {0,0,0,0};
        axr = MFMA(x0, bwrx[0],  axr); axu = MFMA(x0, bwux[0],  axu);
        axr = MFMA(x1, bwrx[4],  axr); axu = MFMA(x1, bwux[4],  axu);
        axr = MFMA(x2, bwrx[8],  axr); axu = MFMA(x2, bwux[8],  axu);
        axr = MFMA(x3, bwrx[12], axr); axu = MFMA(x3, bwux[12], axu);

        f4v hr0 = {0,0,0,0}, hr1 = {0,0,0,0}, hu0 = {0,0,0,0}, hu1 = {0,0,0,0};
        if (t > 0) {
            const unsigned eA = cls_pat((t - 1) & 3);
            WAIT_VM(0);
            unsigned m = check8(hb, eA);
            while (__any(m != 0)) {              // retry only stale lines; wait paces spin
#pragma unroll
                for (int j = 0; j < 8; ++j)
                    if (m & (1u << j)) hb[j] = cload16(hp + (size_t)j * 32);
                WAIT_VM(0);
                m = check8(hb, eA);
            }
            hr0 = MFMA(B16(hb[0]), bwrh[0],  hr0); hu0 = MFMA(B16(hb[0]), bwuh[0],  hu0);
            hr1 = MFMA(B16(hb[1]), bwrh[4],  hr1); hu1 = MFMA(B16(hb[1]), bwuh[4],  hu1);
            hr0 = MFMA(B16(hb[2]), bwrh[8],  hr0); hu0 = MFMA(B16(hb[2]), bwuh[8],  hu0);
            hr1 = MFMA(B16(hb[3]), bwrh[12], hr1); hu1 = MFMA(B16(hb[3]), bwuh[12], hu1);
            hr0 = MFMA(B16(hb[4]), bwrh[16], hr0); hu0 = MFMA(B16(hb[4]), bwuh[16], hu0);
            hr1 = MFMA(B16(hb[5]), bwrh[20], hr1); hu1 = MFMA(B16(hb[5]), bwuh[20], hu1);
            hr0 = MFMA(B16(hb[6]), bwrh[24], hr0); hu0 = MFMA(B16(hb[6]), bwuh[24], hu0);
            hr1 = MFMA(B16(hb[7]), bwrh[28], hr1); hu1 = MFMA(B16(hb[7]), bwuh[28], hu1);
        }
        const float hinv = cls_inv((t - 1) & 3);  // exact 2^-32c; t==0: h-accs are zero
        f4v pr = (axr) + (hr0 + hr1) * hinv;
        f4v pu = (axu) + (hu0 + hu1) * hinv;

        // ---- cross-wave K-reduction (r7-identical) ----
        if (ks > 0) {
#pragma unroll
            for (int i = 0; i < 4; ++i) {
                sP[ks - 1][rt][0][lq * 4 + i][l15] = pr[i];
                sP[ks - 1][rt][1][lq * 4 + i][l15] = pu[i];
            }
        }
        __syncthreads();                             // S1: A partials ready
        float zr[4], zu[4];
        if (ks == 0) {
#pragma unroll
            for (int i = 0; i < 4; ++i) {
                int rr = lq * 4 + i;
                zr[i] = pr[i] + sP[0][rt][0][rr][l15] + sP[1][rt][0][rr][l15]
                              + sP[2][rt][0][rr][l15] + bgr;
                zu[i] = pu[i] + sP[0][rt][1][rr][l15] + sP[1][rt][1][rr][l15]
                              + sP[2][rt][1][rr][l15] + bgu;
            }
        }
        __syncthreads();                             // S2: sP free for phase B
        const float sEnc = cls_scale(t & 3);
        if (ks == 0) {
#pragma unroll
            for (int i = 0; i < 4; ++i) {
                float r = 1.f / (1.f + __expf(-zr[i]));
                ureg[i] = 1.f / (1.f + __expf(-zu[i]));
                __hip_bfloat16 hb16 = __float2bfloat16(enc(r * hprev[i], sEnc));
                sStage[rt][lq * 4 + i][l15] = *(unsigned short*)&hb16;
            }
            if (t > 0) {                             // rh(0) never read
                int prow = lane >> 2, pc4 = (lane & 3) * 4;
                u2v v = *reinterpret_cast<const u2v*>(&sStage[rt][prow][pc4]);  // same-wave LDS
                cstore8(rpub + (size_t)(roff + prow) * HH + bcol0 + pc4, v);
                // no drain, no flag — consumers validate the data itself
            }
        }

        // ========== Phase B: issue rh loads -> x-MFMAs in shadow -> validate-spin ==========
        u4v rb[8];
        const unsigned short* rp = rpub + (size_t)arow * HH + ks * 256 + lq * 8;
        if (t > 0) {
#pragma unroll
            for (int j = 0; j < 8; ++j) rb[j] = cload16(rp + (size_t)j * 32);
        }
        f4v cx0 = {0,0,0,0}, cx1 = {0,0,0,0};
        cx0 = MFMA(x0, bwcx[0],  cx0); cx1 = MFMA(x1, bwcx[4],  cx1);
        cx0 = MFMA(x2, bwcx[8],  cx0); cx1 = MFMA(x3, bwcx[12], cx1);

        f4v ch0 = {0,0,0,0}, ch1 = {0,0,0,0};
        if (t > 0) {
            const unsigned eB = cls_pat(t & 3);
            WAIT_VM(0);
            unsigned m = check8(rb, eB);
            while (__any(m != 0)) {
#pragma unroll
                for (int j = 0; j < 8; ++j)
                    if (m & (1u << j)) rb[j] = cload16(rp + (size_t)j * 32);
                WAIT_VM(0);
                m = check8(rb, eB);
            }
            ch0 = MFMA(B16(rb[0]), bwch[0],  ch0); ch1 = MFMA(B16(rb[1]), bwch[4],  ch1);
            ch0 = MFMA(B16(rb[2]), bwch[8],  ch0); ch1 = MFMA(B16(rb[3]), bwch[12], ch1);
            ch0 = MFMA(B16(rb[4]), bwch[16], ch0); ch1 = MFMA(B16(rb[5]), bwch[20], ch1);
            ch0 = MFMA(B16(rb[6]), bwch[24], ch0); ch1 = MFMA(B16(rb[7]), bwch[28], ch1);
        }
        const float rinv = cls_inv(t & 3);
        f4v pc = (cx0 + cx1) + (ch0 + ch1) * rinv;

        if (ks > 0) {
#pragma unroll
            for (int i = 0; i < 4; ++i) sP[ks - 1][rt][0][lq * 4 + i][l15] = pc[i];
        }
        __syncthreads();                             // S3: B partials ready
        float zc[4];
        if (ks == 0) {
#pragma unroll
            for (int i = 0; i < 4; ++i) {
                int rr = lq * 4 + i;
                zc[i] = pc[i] + sP[0][rt][0][rr][l15] + sP[1][rt][0][rr][l15]
                              + sP[2][rt][0][rr][l15] + bcv;
            }
        }
        __syncthreads();                             // S4: sP free for next step
        if (ks == 0) {
#pragma unroll
            for (int i = 0; i < 4; ++i) {
                float e = __expf(2.f * zc[i]);
                float cv = 1.f - 2.f / (e + 1.f);
                float hn = ureg[i] * hprev[i] + (1.f - ureg[i]) * cv;
                hprev[i] = hn;
                __hip_bfloat16 hb16 = __float2bfloat16(enc(hn, sEnc));
                sStage[rt][lq * 4 + i][l15] = *(unsigned short*)&hb16;
            }
            int prow = lane >> 2, pc4 = (lane & 3) * 4;
            u2v v = *reinterpret_cast<const u2v*>(&sStage[rt][prow][pc4]);      // same-wave LDS
            cstore8(hpub + (size_t)(roff + prow) * HH + bcol0 + pc4, v);
            // no drain, no flag
            // out stores — off the rendezvous critical path (decoded domain)
#pragma unroll
            for (int i = 0; i < 4; ++i) {
                int row = roff + lq * 4 + i;
                out[(size_t)row * (TT * HH) + (size_t)t * HH + ccol] = hprev[i];
            }
        }
    }
}

// ---------------------------------------------------------------------------
extern "C" void kernel_launch(void* const* d_in, const int* in_sizes, int n_in,
                              void* d_out, int out_size, void* d_ws, size_t ws_size,
                              hipStream_t stream) {
    const float* X  = (const float*)d_in[0];
    const float* gk = (const float*)d_in[1];
    const float* gb = (const float*)d_in[2];
    const float* ck = (const float*)d_in[3];
    const float* cb = (const float*)d_in[4];
    float* out = (float*)d_out;
    char* ws = (char*)d_ws;
    if (ws_size < NEED) return;

    unsigned short* WgT  = (unsigned short*)(ws + OFF_WGT);
    unsigned short* WcT  = (unsigned short*)(ws + OFF_WCT);
    unsigned short* Xbf  = (unsigned short*)(ws + OFF_XBF);
    unsigned short* hpub = (unsigned short*)(ws + OFF_HPB);
    unsigned short* rpub = (unsigned short*)(ws + OFF_RPB);

    // 0x7F7F -> exp[7:5] = 0b111: fails every generation class (cross-launch safe)
    hipMemsetAsync(hpub, 0x7F, 2 * SZ_PUB, stream);

    dim3 tb(256);
    wtr_kernel<<<dim3(2 * HH / 32, KK / 32), tb, 0, stream>>>(gk, WgT, 2 * HH);
    wtr_kernel<<<dim3(HH / 32, KK / 32), tb, 0, stream>>>(ck, WcT, HH);
    xconv_kernel<<<(BB * TT * DD) / (256 * 4), tb, 0, stream>>>(X, Xbf);

    gru_kernel<<<NBLK, dim3(TPB), 0, stream>>>(Xbf, WgT, WcT, gb, cb, out,
                                               hpub, rpub);
}